// Round 13
// baseline (210.472 us; speedup 1.0000x reference)
//
#include <hip/hip_runtime.h>

// B=2, S=2048, E=1024, H=16, D=64
#define SEQ 2048
#define EMB 1024
#define KDIM 1024
#define CF 0.180336880111113f  // (1/sqrt(64)) * log2(e), folded into Q

typedef __attribute__((ext_vector_type(8))) short short8_t;
typedef __attribute__((ext_vector_type(4))) float floatx4;
typedef __attribute__((ext_vector_type(4))) unsigned short ushort4_t;
typedef __attribute__((ext_vector_type(4))) unsigned int uivec4;

#define GLOAD16(gp, lp)                                                        \
  __builtin_amdgcn_global_load_lds(                                            \
      (const __attribute__((address_space(1))) void*)(gp),                     \
      (__attribute__((address_space(3))) void*)(lp), 16, 0, 0)

#define WGBAR()                                   \
  do {                                            \
    __asm__ __volatile__("" ::: "memory");        \
    __builtin_amdgcn_s_barrier();                 \
    __asm__ __volatile__("" ::: "memory");        \
  } while (0)

static __device__ __forceinline__ unsigned short f2bf(float x) {
  unsigned int u = __float_as_uint(x);
  return (unsigned short)((u + 0x7fffu + ((u >> 16) & 1u)) >> 16);
}

static __device__ __forceinline__ short8_t mk_pb(unsigned int a, unsigned int b,
                                                 unsigned int c, unsigned int d) {
  uivec4 t;
  t[0] = a; t[1] = b; t[2] = c; t[3] = d;
  return __builtin_bit_cast(short8_t, t);
}

// pack bf16(trunc) pair: low = hi16(p0), high = hi16(p1), one v_perm_b32
static __device__ __forceinline__ unsigned int pack_bf(float p0, float p1) {
  return __builtin_amdgcn_perm(__float_as_uint(p1), __float_as_uint(p0),
                               0x07060302u);
}

// ---------------------------------------------------------------------------
// Fused prepass: blockIdx 0..4095   -> hs fp32 -> bf16
//                4096..4863         -> c_attn_w [1024,3072] -> w1t [3072,1024]
//                4864..5119         -> c_proj_w [1024,1024] -> w2t [1024,1024]
// ---------------------------------------------------------------------------
static __device__ __forceinline__ void tconv_tile(
    const float* __restrict__ W, unsigned short* __restrict__ T, int N, int K,
    int n0, int k0, int tid) {
  __shared__ float Tl[64][65];
  const int lx = tid & 15, ly = tid >> 4;
#pragma unroll
  for (int u = 0; u < 4; ++u) {
    int r = u * 16 + ly;
    float4 v = *(const float4*)&W[(size_t)(k0 + r) * N + n0 + lx * 4];
    Tl[r][lx * 4 + 0] = v.x;
    Tl[r][lx * 4 + 1] = v.y;
    Tl[r][lx * 4 + 2] = v.z;
    Tl[r][lx * 4 + 3] = v.w;
  }
  __syncthreads();
#pragma unroll
  for (int u = 0; u < 4; ++u) {
    int n = u * 16 + ly;
    ushort4_t h;
#pragma unroll
    for (int v = 0; v < 4; ++v) h[v] = f2bf(Tl[lx * 4 + v][n]);
    *(ushort4_t*)&T[(size_t)(n0 + n) * K + k0 + lx * 4] = h;
  }
}

__global__ __launch_bounds__(256) void prep(
    const float* __restrict__ hs, const float* __restrict__ caw,
    const float* __restrict__ cpw, unsigned short* __restrict__ hsb,
    unsigned short* __restrict__ w1t, unsigned short* __restrict__ w2t) {
  const int bid = blockIdx.x, tid = threadIdx.x;
  if (bid < 4096) {
    const int i = bid * 256 + tid;
    float4 v = *(const float4*)&hs[(size_t)i * 4];
    ushort4_t h = {f2bf(v.x), f2bf(v.y), f2bf(v.z), f2bf(v.w)};
    *(ushort4_t*)&hsb[(size_t)i * 4] = h;
  } else if (bid < 4864) {
    const int idx = bid - 4096;
    tconv_tile(caw, w1t, 3 * EMB, EMB, (idx % 48) * 64, (idx / 48) * 64, tid);
  } else {
    const int idx = bid - 4864;
    tconv_tile(cpw, w2t, EMB, EMB, (idx % 16) * 64, (idx / 16) * 64, tid);
  }
}

// ---------------------------------------------------------------------------
// bf16 MFMA GEMM, BK=64 -> 16 ROUNDS (R10-proven win).  Double-buffered LDS
// (MODE 0: 64 KB; MODE 2: 48 KB), depth-1 prefetch, one barrier/round.
// Rows are 128 B; staging uses the 8-row GLOAD16 pattern with XOR swizzle.
// Tile 128 x BN.  A: [M,1024] bf16;  Bt: [N,1024] bf16 (W^T).
// MODE 0 (BN=128, 768 blocks): cols<2048 -> qk (q scaled CF); else vt
//   (KEY-PERMUTED per 64-key tile -> attn consumes P from registers).
// MODE 2 (BN=64, 512 blocks): fp32 out [M,1024].
// ---------------------------------------------------------------------------
template <int MODE, int BN>
__global__ __launch_bounds__(256, MODE == 0 ? 2 : 3) void gemm_pl(
    const unsigned short* __restrict__ Ag, const unsigned short* __restrict__ Bg,
    const float* __restrict__ bias, float* __restrict__ outF,
    unsigned short* __restrict__ qk, unsigned short* __restrict__ vt) {
  __shared__ __attribute__((aligned(16))) unsigned short Ah[2][128 * 64];
  __shared__ __attribute__((aligned(16))) unsigned short Bh[2][BN * 64];
  const int NJ = BN / 32;  // j-frag groups per wave

  const int tid = threadIdx.x;
  const int w = tid >> 6, lane = tid & 63;
  const int quad = lane >> 4, c = lane & 15;
  const int rk = c & 7;

  // XCD swizzle: rectangles per XCD sized to (mostly) fit the 4 MB L2
  int bm, bn;
  {
    const int L = blockIdx.x, x = L & 7, g = L >> 3;
    if (MODE == 0) {  // 768 blocks: per-XCD 16bm x 6bn (A 4MB + B 1.5MB)
      bm = ((x & 1) * 16 + (g & 15)) * 128;
      bn = ((x >> 1) * 6 + (g >> 4)) * 128;
    } else {  // 512 blocks: per-XCD 8bm x 8bn (A 2MB + B 1MB)
      bm = ((x & 3) * 8 + (g & 7)) * 128;
      bn = ((x >> 2) * 8 + (g >> 3)) * 64;
    }
  }
  const int wm = (w >> 1) * 64, wn = (w & 1) * (BN / 2);

  // staging: waves 0,1 -> A halves (64 rows, 8 GLOAD16); waves 2,3 -> B
  // halves (BN/2 rows, BN/16 GLOAD16).
  const unsigned short* gsrc = (w < 2) ? Ag : Bg;
  const int lbo = (w < 2) ? (w & 1) * 64 * 64 : (w & 1) * (BN / 2) * 64;
  const int rbase = (w < 2) ? (bm + (w & 1) * 64) : (bn + (w & 1) * (BN / 2));
  const int nloads = (w < 2) ? 8 : (BN / 16);
  const int srow = lane >> 3;           // 0..7
  const int sblkg = (lane & 7) ^ srow;  // XOR chunk swizzle (128 B rows)
  const char* gp0 = (const char*)(gsrc + (size_t)(rbase + srow) * KDIM) + sblkg * 16;

  floatx4 acc[4][NJ];
  const floatx4 z = {0.f, 0.f, 0.f, 0.f};
#pragma unroll
  for (int i = 0; i < 4; ++i)
#pragma unroll
    for (int j = 0; j < NJ; ++j) acc[i][j] = z;

#define STAGE_G(buf, kt)                                                       \
  do {                                                                         \
    unsigned short* ld = ((w < 2) ? Ah[buf] : Bh[buf]) + lbo;                  \
    const char* gp = gp0 + (size_t)(kt) * 128;                                 \
    for (int i_ = 0; i_ < nloads; ++i_)                                        \
      GLOAD16(gp + (size_t)i_ * 8 * (KDIM * 2), &ld[i_ * 512]);                \
  } while (0)

  STAGE_G(0, 0);

  for (int t = 0; t < 16; ++t) {
    __asm__ __volatile__("s_waitcnt vmcnt(0)" ::: "memory");  // stage-t landed
    WGBAR();  // all waves: stage-t landed AND compute t-1 finished
    if (t < 15) STAGE_G((t + 1) & 1, t + 1);  // overwrites buf read in t-1
    const unsigned short* Ac = Ah[t & 1];
    const unsigned short* Bc = Bh[t & 1];

#pragma unroll
    for (int kd = 0; kd < 2; ++kd) {
      const int oct = ((4 * kd + quad) ^ rk) * 8;
      short8_t a[4], b[NJ];
#pragma unroll
      for (int i = 0; i < 4; ++i)
        a[i] = *(const short8_t*)&Ac[(wm + 16 * i + c) * 64 + oct];
#pragma unroll
      for (int j = 0; j < NJ; ++j)
        b[j] = *(const short8_t*)&Bc[(wn + 16 * j + c) * 64 + oct];
      // transposed: lane = A-row (m), regs = 4 consecutive B-rows (n)
#pragma unroll
      for (int i = 0; i < 4; ++i)
#pragma unroll
        for (int j = 0; j < NJ; ++j)
          acc[i][j] = __builtin_amdgcn_mfma_f32_16x16x32_bf16(b[j], a[i], acc[i][j], 0, 0, 0);
    }
  }
#undef STAGE_G

#pragma unroll
  for (int i = 0; i < 4; ++i) {
    const int row = bm + wm + 16 * i + c;
#pragma unroll
    for (int j = 0; j < NJ; ++j) {
      const int col0 = bn + wn + 16 * j + quad * 4;
      floatx4 v = acc[i][j] + *(const floatx4*)&bias[col0];
      if (MODE == 0) {
        if (col0 < 1024) v = v * CF;
        if (col0 < 2048) {
          ushort4_t pk = {f2bf(v[0]), f2bf(v[1]), f2bf(v[2]), f2bf(v[3])};
          *(ushort4_t*)&qk[(size_t)row * 2048 + col0] = pk;
        } else {
          const int c2 = col0 - 2048, hh = c2 >> 6, d0 = c2 & 63;
          const int bb = row >> 11, s = row & 2047;
          // Key permutation within each 64-key tile so the attn PV MFMA can
          // use lane-local P registers as the B operand directly.
          // Logical slot lam (bits [kq][q1 q0][a][r1 r0]) holds global key
          // j (bits [kq][a][q1 q0][r1 r0]):  lam = invpi(j).
          const int j = s & 63;
          const int lam = (j & 0x20) | ((j & 0x0C) << 1) | ((j & 0x10) >> 2) | (j & 3);
          const int sp = (s & ~63) | lam;
          unsigned short* vb = &vt[((size_t)(bb * 16 + hh) * 64 + d0) * 2048 + sp];
          vb[0 * 2048] = f2bf(v[0]);
          vb[1 * 2048] = f2bf(v[1]);
          vb[2 * 2048] = f2bf(v[2]);
          vb[3 * 2048] = f2bf(v[3]);
        }
      } else {
        *(floatx4*)&outF[(size_t)row * 1024 + col0] = v;
      }
    }
  }
}

// ---------------------------------------------------------------------------
// bf16 MFMA flash attention, WAVE-PRIVATE PIPELINES (the R11 theory: every
// barrier-synced variant lands 44-47 us with MfmaUtil~33+VALUBusy~34 — the
// block-wide barrier convoy serializes the MFMA and VALU phases.  Remove
// the barrier entirely.)
// 256 blocks x 512 thr = 1 block/CU; wave w owns q-rows q0+32w..+31 and
// iterates ALL 2048 keys (64 tiles of 32) at its own pace:
//  - K: wave-private LDS slice, 3 buffers of 4 KB, staged via 4 GLOAD16.
//  - V: prefetched into REGISTERS (4x short8) straight from L1/L2 (vt is
//    XCD-local, 2 MB working set) — no LDS, no bank conflicts, and the
//    vt key-permutation keeps P lane-local (attn8b's verified mapping).
//  - counted per-wave vmcnt(4): V(t),K(t) landed; K(t+1) stays in flight.
//  - NO s_barrier anywhere; no split-K -> no combine epilogue.
// ---------------------------------------------------------------------------
__global__ __launch_bounds__(512, 1) void attn12(
    const unsigned short* __restrict__ qk, const unsigned short* __restrict__ vt,
    unsigned short* __restrict__ ao) {
  __shared__ __attribute__((aligned(16))) unsigned short Kpriv[8 * 3 * 2048];  // 96 KB

  const int tid = threadIdx.x;
  const int w = tid >> 6, lane = tid & 63, quad = lane >> 4, c = lane & 15;
  const int L = blockIdx.x, x = L & 7, g = L >> 3;
  const int hb = x * 4 + (g >> 3);   // 4 (h,b) groups per XCD
  const int h = hb & 15, b = hb >> 4;
  const int q0 = (g & 7) * 256 + w * 32;  // this wave's 32 q-rows
  const int rk = c & 7;

  short8_t qf[2][2];
#pragma unroll
  for (int mi = 0; mi < 2; ++mi) {
    const size_t qr = ((size_t)(b * SEQ + q0 + mi * 16 + c)) * 2048 + h * 64 + quad * 8;
    qf[mi][0] = *(const short8_t*)&qk[qr];
    qf[mi][1] = *(const short8_t*)&qk[qr + 32];
  }
  __asm__ __volatile__("s_waitcnt vmcnt(0)" ::: "memory");  // clean vmcnt queue

  floatx4 O[2][4], Osum[2];
  const floatx4 z = {0.f, 0.f, 0.f, 0.f};
#pragma unroll
  for (int mi = 0; mi < 2; ++mi) {
    Osum[mi] = z;
#pragma unroll
    for (int dg = 0; dg < 4; ++dg) O[mi][dg] = z;
  }
  short8_t ones;
#pragma unroll
  for (int e = 0; e < 8; ++e) ones[e] = (short)0x3F80;  // bf16 1.0

  const int srow = lane >> 3;           // 0..7
  const int sblkg = (lane & 7) ^ srow;  // staging chunk swizzle (128 B K rows)
  const unsigned short* gK = qk + (size_t)b * SEQ * 2048 + 1024 + h * 64;
  const unsigned short* gV = vt + (size_t)(b * 16 + h) * 64 * 2048;
  unsigned short* Kb = &Kpriv[w * 3 * 2048];  // wave-private 12 KB

  // stage K tile t (32 keys x 64 d = 4 KB) into private buf: 4 GLOAD16
#define STK(buf, t)                                                            \
  do {                                                                         \
    const unsigned short* g0_ = gK + (size_t)((t) * 32 + srow) * 2048 + sblkg * 8; \
    unsigned short* l0_ = Kb + (buf) * 2048;                                   \
    GLOAD16(g0_, l0_);                                                         \
    GLOAD16(g0_ + (size_t)8 * 2048, l0_ + 512);                                \
    GLOAD16(g0_ + (size_t)16 * 2048, l0_ + 1024);                              \
    GLOAD16(g0_ + (size_t)24 * 2048, l0_ + 1536);                              \
  } while (0)

  // V fragments for tile t -> registers (4 x 16B, L1/L2-resident)
#define LDV(vf_, t)                                                            \
  do {                                                                         \
    _Pragma("unroll")                                                          \
    for (int dg_ = 0; dg_ < 4; ++dg_)                                          \
      vf_[dg_] = *(const short8_t*)&gV[(size_t)(dg_ * 16 + c) * 2048 +         \
                                       (t) * 32 + quad * 8];                   \
  } while (0)

  short8_t vfA[4], vfB[4];
  // prime: issue order [K(0), V(0), K(1)] so vmcnt(4) at round 0 means
  // K(0)+V(0) done, K(1) in flight.
  STK(0, 0);
  __asm__ __volatile__("" ::: "memory");
  LDV(vfA, 0);
  __asm__ __volatile__("" ::: "memory");
  STK(1, 1);

  // one round; cur = V regs for tile t, nxt = V regs to fill for t+1
#define ROUND(t, cur, nxt)                                                     \
  do {                                                                         \
    __asm__ __volatile__("s_waitcnt vmcnt(4)" ::: "memory");                   \
    LDV(nxt, ((t) + 1) & 63);                                                  \
    __asm__ __volatile__("" ::: "memory");                                     \
    STK(((t) + 2) % 3, ((t) + 2) & 63);                                        \
    __asm__ __volatile__("" ::: "memory");                                     \
    const unsigned short* Kc = Kb + ((t) % 3) * 2048;                          \
    floatx4 S[2][2];                                                           \
    S[0][0] = z; S[0][1] = z; S[1][0] = z; S[1][1] = z;                        \
    _Pragma("unroll")                                                          \
    for (int kd = 0; kd < 2; ++kd) {                                           \
      const int oct = ((4 * kd + quad) ^ rk) * 8;                              \
      _Pragma("unroll")                                                        \
      for (int jg = 0; jg < 2; ++jg) {                                         \
        short8_t kf = *(const short8_t*)&Kc[(jg * 16 + c) * 64 + oct];         \
        _Pragma("unroll")                                                      \
        for (int mi = 0; mi < 2; ++mi)                                         \
          S[mi][jg] = __builtin_amdgcn_mfma_f32_16x16x32_bf16(                 \
              kf, qf[mi][kd], S[mi][jg], 0, 0, 0);                             \
      }                                                                        \
    }                                                                          \
    _Pragma("unroll")                                                          \
    for (int mi = 0; mi < 2; ++mi) {                                           \
      unsigned int pw[2][2];                                                   \
      _Pragma("unroll")                                                        \
      for (int jg = 0; jg < 2; ++jg) {                                         \
        float p0 = __builtin_amdgcn_exp2f(S[mi][jg][0]);                       \
        float p1 = __builtin_amdgcn_exp2f(S[mi][jg][1]);                       \
        float p2 = __builtin_amdgcn_exp2f(S[mi][jg][2]);                       \
        float p3 = __builtin_amdgcn_exp2f(S[mi][jg][3]);                       \
        pw[jg][0] = pack_bf(p0, p1);                                           \
        pw[jg][1] = pack_bf(p2, p3);                                           \
      }                                                                        \
      short8_t pb = mk_pb(pw[0][0], pw[0][1], pw[1][0], pw[1][1]);             \
      Osum[mi] = __builtin_amdgcn_mfma_f32_16x16x32_bf16(ones, pb, Osum[mi], 0, 0, 0); \
      _Pragma("unroll")                                                        \
      for (int dg = 0; dg < 4; ++dg)                                           \
        O[mi][dg] = __builtin_amdgcn_mfma_f32_16x16x32_bf16(cur[dg], pb, O[mi][dg], 0, 0, 0); \
    }                                                                          \
  } while (0)

  for (int t = 0; t < 64; t += 2) {
    ROUND(t, vfA, vfB);
    ROUND(t + 1, vfB, vfA);
  }
#undef ROUND
#undef LDV
#undef STK

  __asm__ __volatile__("s_waitcnt vmcnt(0)" ::: "memory");  // drain trailing DMA

  // epilogue: full softmax sum per wave -> direct normalized store
#pragma unroll
  for (int mi = 0; mi < 2; ++mi) {
    const float inv = 1.0f / Osum[mi][0];
    const size_t row = (size_t)b * SEQ + q0 + mi * 16 + c;
#pragma unroll
    for (int dg = 0; dg < 4; ++dg) {
      ushort4_t ov = {f2bf(O[mi][dg][0] * inv), f2bf(O[mi][dg][1] * inv),
                      f2bf(O[mi][dg][2] * inv), f2bf(O[mi][dg][3] * inv)};
      *(ushort4_t*)&ao[row * EMB + h * 64 + dg * 16 + quad * 4] = ov;
    }
  }
}

// ---------------------------------------------------------------------------
extern "C" void kernel_launch(void* const* d_in, const int* in_sizes, int n_in,
                              void* d_out, int out_size, void* d_ws, size_t ws_size,
                              hipStream_t stream) {
  const float* hs = (const float*)d_in[0];        // [B,S,E]
  const float* c_attn_w = (const float*)d_in[1];  // [E,3E]
  const float* c_attn_b = (const float*)d_in[2];  // [3E]
  const float* c_proj_w = (const float*)d_in[3];  // [E,E]
  const float* c_proj_b = (const float*)d_in[4];  // [E]
  float* out = (float*)d_out;                     // [B,S,E] fp32

  char* ws = (char*)d_ws;
  unsigned short* hsb = (unsigned short*)(ws + 0);         // 8.39 MB [B,S,E] bf16
  unsigned short* qk  = (unsigned short*)(ws + 8388608);   // 16.8 MB [B,S,2048]
  unsigned short* vt  = (unsigned short*)(ws + 25165824);  // 8.39 MB [B,H,D,S] (key-permuted per 64-tile)
  unsigned short* aob = (unsigned short*)(ws + 33554432);  // 8.39 MB [B,S,E] bf16
  unsigned short* w1t = (unsigned short*)(ws + 41943040);  // 6.29 MB [3072,1024]
  unsigned short* w2t = (unsigned short*)(ws + 48234496);  // 2.10 MB [1024,1024]

  // 1) fused prepass: hs->bf16, transpose+convert both weight matrices
  prep<<<5120, 256, 0, stream>>>(hs, c_attn_w, c_proj_w, hsb, w1t, w2t);
  // 2) QKV GEMM (BK=64, 16 rounds) -> qk (q pre-scaled by CF) + vt
  gemm_pl<0, 128><<<768, 256, 0, stream>>>(hsb, w1t, c_attn_b, nullptr, qk, vt);
  // 3) attention: wave-private barrier-free pipelines -> aob bf16
  attn12<<<256, 512, 0, stream>>>(qk, vt, aob);
  // 4) output projection (BK=64, 16 rounds) -> fp32 out
  gemm_pl<2, 64><<<512, 256, 0, stream>>>(aob, w2t, c_proj_b, out, nullptr, nullptr);
}

// Round 14
// 173.622 us; speedup vs baseline: 1.2122x; 1.2122x over previous
//
#include <hip/hip_runtime.h>

// B=2, S=2048, E=1024, H=16, D=64
#define SEQ 2048
#define EMB 1024
#define KDIM 1024
#define CF 0.180336880111113f  // (1/sqrt(64)) * log2(e), folded into Q

typedef __attribute__((ext_vector_type(8))) short short8_t;
typedef __attribute__((ext_vector_type(4))) float floatx4;
typedef __attribute__((ext_vector_type(4))) unsigned short ushort4_t;
typedef __attribute__((ext_vector_type(4))) unsigned int uivec4;

#define GLOAD16(gp, lp)                                                        \
  __builtin_amdgcn_global_load_lds(                                            \
      (const __attribute__((address_space(1))) void*)(gp),                     \
      (__attribute__((address_space(3))) void*)(lp), 16, 0, 0)

#define WGBAR()                                   \
  do {                                            \
    __asm__ __volatile__("" ::: "memory");        \
    __builtin_amdgcn_s_barrier();                 \
    __asm__ __volatile__("" ::: "memory");        \
  } while (0)

static __device__ __forceinline__ unsigned short f2bf(float x) {
  unsigned int u = __float_as_uint(x);
  return (unsigned short)((u + 0x7fffu + ((u >> 16) & 1u)) >> 16);
}

static __device__ __forceinline__ short8_t mk_pb(unsigned int a, unsigned int b,
                                                 unsigned int c, unsigned int d) {
  uivec4 t;
  t[0] = a; t[1] = b; t[2] = c; t[3] = d;
  return __builtin_bit_cast(short8_t, t);
}

// pack bf16(trunc) pair: low = hi16(p0), high = hi16(p1), one v_perm_b32
static __device__ __forceinline__ unsigned int pack_bf(float p0, float p1) {
  return __builtin_amdgcn_perm(__float_as_uint(p1), __float_as_uint(p0),
                               0x07060302u);
}

// ---------------------------------------------------------------------------
// Fused prepass: blockIdx 0..4095   -> hs fp32 -> bf16
//                4096..4863         -> c_attn_w [1024,3072] -> w1t [3072,1024]
//                4864..5119         -> c_proj_w [1024,1024] -> w2t [1024,1024]
// ---------------------------------------------------------------------------
static __device__ __forceinline__ void tconv_tile(
    const float* __restrict__ W, unsigned short* __restrict__ T, int N, int K,
    int n0, int k0, int tid) {
  __shared__ float Tl[64][65];
  const int lx = tid & 15, ly = tid >> 4;
#pragma unroll
  for (int u = 0; u < 4; ++u) {
    int r = u * 16 + ly;
    float4 v = *(const float4*)&W[(size_t)(k0 + r) * N + n0 + lx * 4];
    Tl[r][lx * 4 + 0] = v.x;
    Tl[r][lx * 4 + 1] = v.y;
    Tl[r][lx * 4 + 2] = v.z;
    Tl[r][lx * 4 + 3] = v.w;
  }
  __syncthreads();
#pragma unroll
  for (int u = 0; u < 4; ++u) {
    int n = u * 16 + ly;
    ushort4_t h;
#pragma unroll
    for (int v = 0; v < 4; ++v) h[v] = f2bf(Tl[lx * 4 + v][n]);
    *(ushort4_t*)&T[(size_t)(n0 + n) * K + k0 + lx * 4] = h;
  }
}

__global__ __launch_bounds__(256) void prep(
    const float* __restrict__ hs, const float* __restrict__ caw,
    const float* __restrict__ cpw, unsigned short* __restrict__ hsb,
    unsigned short* __restrict__ w1t, unsigned short* __restrict__ w2t) {
  const int bid = blockIdx.x, tid = threadIdx.x;
  if (bid < 4096) {
    const int i = bid * 256 + tid;
    float4 v = *(const float4*)&hs[(size_t)i * 4];
    ushort4_t h = {f2bf(v.x), f2bf(v.y), f2bf(v.z), f2bf(v.w)};
    *(ushort4_t*)&hsb[(size_t)i * 4] = h;
  } else if (bid < 4864) {
    const int idx = bid - 4096;
    tconv_tile(caw, w1t, 3 * EMB, EMB, (idx % 48) * 64, (idx / 48) * 64, tid);
  } else {
    const int idx = bid - 4864;
    tconv_tile(cpw, w2t, EMB, EMB, (idx % 16) * 64, (idx / 16) * 64, tid);
  }
}

// ---------------------------------------------------------------------------
// bf16 MFMA GEMM, BK=64 -> 16 ROUNDS (R10-proven win).  Double-buffered LDS
// (MODE 0: 64 KB; MODE 2: 48 KB), depth-1 prefetch, one barrier/round.
// Rows are 128 B; staging uses the 8-row GLOAD16 pattern with XOR swizzle.
// Tile 128 x BN.  A: [M,1024] bf16;  Bt: [N,1024] bf16 (W^T).
// MODE 0 (BN=128, 768 blocks): cols<2048 -> qk (q scaled CF); else vt
//   (KEY-PERMUTED per 64-key tile -> attn consumes P from registers).
// MODE 2 (BN=64, 512 blocks): fp32 out [M,1024].
// ---------------------------------------------------------------------------
template <int MODE, int BN>
__global__ __launch_bounds__(256, MODE == 0 ? 2 : 3) void gemm_pl(
    const unsigned short* __restrict__ Ag, const unsigned short* __restrict__ Bg,
    const float* __restrict__ bias, float* __restrict__ outF,
    unsigned short* __restrict__ qk, unsigned short* __restrict__ vt) {
  __shared__ __attribute__((aligned(16))) unsigned short Ah[2][128 * 64];
  __shared__ __attribute__((aligned(16))) unsigned short Bh[2][BN * 64];
  const int NJ = BN / 32;  // j-frag groups per wave

  const int tid = threadIdx.x;
  const int w = tid >> 6, lane = tid & 63;
  const int quad = lane >> 4, c = lane & 15;
  const int rk = c & 7;

  // XCD swizzle: rectangles per XCD sized to (mostly) fit the 4 MB L2
  int bm, bn;
  {
    const int L = blockIdx.x, x = L & 7, g = L >> 3;
    if (MODE == 0) {  // 768 blocks: per-XCD 16bm x 6bn (A 4MB + B 1.5MB)
      bm = ((x & 1) * 16 + (g & 15)) * 128;
      bn = ((x >> 1) * 6 + (g >> 4)) * 128;
    } else {  // 512 blocks: per-XCD 8bm x 8bn (A 2MB + B 1MB)
      bm = ((x & 3) * 8 + (g & 7)) * 128;
      bn = ((x >> 2) * 8 + (g >> 3)) * 64;
    }
  }
  const int wm = (w >> 1) * 64, wn = (w & 1) * (BN / 2);

  // staging: waves 0,1 -> A halves (64 rows, 8 GLOAD16); waves 2,3 -> B
  // halves (BN/2 rows, BN/16 GLOAD16).
  const unsigned short* gsrc = (w < 2) ? Ag : Bg;
  const int lbo = (w < 2) ? (w & 1) * 64 * 64 : (w & 1) * (BN / 2) * 64;
  const int rbase = (w < 2) ? (bm + (w & 1) * 64) : (bn + (w & 1) * (BN / 2));
  const int nloads = (w < 2) ? 8 : (BN / 16);
  const int srow = lane >> 3;           // 0..7
  const int sblkg = (lane & 7) ^ srow;  // XOR chunk swizzle (128 B rows)
  const char* gp0 = (const char*)(gsrc + (size_t)(rbase + srow) * KDIM) + sblkg * 16;

  floatx4 acc[4][NJ];
  const floatx4 z = {0.f, 0.f, 0.f, 0.f};
#pragma unroll
  for (int i = 0; i < 4; ++i)
#pragma unroll
    for (int j = 0; j < NJ; ++j) acc[i][j] = z;

#define STAGE_G(buf, kt)                                                       \
  do {                                                                         \
    unsigned short* ld = ((w < 2) ? Ah[buf] : Bh[buf]) + lbo;                  \
    const char* gp = gp0 + (size_t)(kt) * 128;                                 \
    for (int i_ = 0; i_ < nloads; ++i_)                                        \
      GLOAD16(gp + (size_t)i_ * 8 * (KDIM * 2), &ld[i_ * 512]);                \
  } while (0)

  STAGE_G(0, 0);

  for (int t = 0; t < 16; ++t) {
    __asm__ __volatile__("s_waitcnt vmcnt(0)" ::: "memory");  // stage-t landed
    WGBAR();  // all waves: stage-t landed AND compute t-1 finished
    if (t < 15) STAGE_G((t + 1) & 1, t + 1);  // overwrites buf read in t-1
    const unsigned short* Ac = Ah[t & 1];
    const unsigned short* Bc = Bh[t & 1];

#pragma unroll
    for (int kd = 0; kd < 2; ++kd) {
      const int oct = ((4 * kd + quad) ^ rk) * 8;
      short8_t a[4], b[NJ];
#pragma unroll
      for (int i = 0; i < 4; ++i)
        a[i] = *(const short8_t*)&Ac[(wm + 16 * i + c) * 64 + oct];
#pragma unroll
      for (int j = 0; j < NJ; ++j)
        b[j] = *(const short8_t*)&Bc[(wn + 16 * j + c) * 64 + oct];
      // transposed: lane = A-row (m), regs = 4 consecutive B-rows (n)
#pragma unroll
      for (int i = 0; i < 4; ++i)
#pragma unroll
        for (int j = 0; j < NJ; ++j)
          acc[i][j] = __builtin_amdgcn_mfma_f32_16x16x32_bf16(b[j], a[i], acc[i][j], 0, 0, 0);
    }
  }
#undef STAGE_G

#pragma unroll
  for (int i = 0; i < 4; ++i) {
    const int row = bm + wm + 16 * i + c;
#pragma unroll
    for (int j = 0; j < NJ; ++j) {
      const int col0 = bn + wn + 16 * j + quad * 4;
      floatx4 v = acc[i][j] + *(const floatx4*)&bias[col0];
      if (MODE == 0) {
        if (col0 < 1024) v = v * CF;
        if (col0 < 2048) {
          ushort4_t pk = {f2bf(v[0]), f2bf(v[1]), f2bf(v[2]), f2bf(v[3])};
          *(ushort4_t*)&qk[(size_t)row * 2048 + col0] = pk;
        } else {
          const int c2 = col0 - 2048, hh = c2 >> 6, d0 = c2 & 63;
          const int bb = row >> 11, s = row & 2047;
          // Key permutation within each 64-key tile so the attn PV MFMA can
          // use lane-local P registers as the B operand directly.
          // Logical slot lam (bits [kq][q1 q0][a][r1 r0]) holds global key
          // j (bits [kq][a][q1 q0][r1 r0]):  lam = invpi(j).
          const int j = s & 63;
          const int lam = (j & 0x20) | ((j & 0x0C) << 1) | ((j & 0x10) >> 2) | (j & 3);
          const int sp = (s & ~63) | lam;
          unsigned short* vb = &vt[((size_t)(bb * 16 + hh) * 64 + d0) * 2048 + sp];
          vb[0 * 2048] = f2bf(v[0]);
          vb[1 * 2048] = f2bf(v[1]);
          vb[2 * 2048] = f2bf(v[2]);
          vb[3 * 2048] = f2bf(v[3]);
        }
      } else {
        *(floatx4*)&outF[(size_t)row * 1024 + col0] = v;
      }
    }
  }
}

// ---------------------------------------------------------------------------
// K/V staging for the megablock: 8 waves, 16 rows each, 2 GLOAD16/wave.
// waves 0..3 -> K rows w*16..+15; waves 4..7 -> V^T d-rows (w-4)*16..+15.
// ---------------------------------------------------------------------------
static __device__ __forceinline__ void stage_kv16(
    int w, int srow, int sblkg, const unsigned short* __restrict__ gK,
    const unsigned short* __restrict__ gV, unsigned short* Kbuf,
    unsigned short* Vbuf, int jt) {
  if (w < 4) {
    const unsigned short* g0 =
        gK + (size_t)(jt * 64 + w * 16 + srow) * 2048 + sblkg * 8;
    unsigned short* l0 = &Kbuf[(w * 16) * 64];
    GLOAD16(g0, l0);
    GLOAD16(g0 + (size_t)8 * 2048, l0 + 8 * 64);
  } else {
    const unsigned short* g0 =
        gV + (size_t)((w - 4) * 16 + srow) * 2048 + jt * 64 + sblkg * 8;
    unsigned short* l0 = &Vbuf[((w - 4) * 16) * 64];
    GLOAD16(g0, l0);
    GLOAD16(g0 + (size_t)8 * 2048, l0 + 8 * 64);
  }
}

// ---------------------------------------------------------------------------
// bf16 MFMA flash attention MEGABLOCK (measured best structure, R9/R11):
// 256 blocks x 512 thr = 1 block/CU; q-tile 256 rows; waves = 4 qh x 2 kh;
// KVBLK=64; triple-buffered K/V, counted vmcnt(2), wrap-around staging;
// in-register P via vt key-permutation; fixed-max softmax.
// R13 change: V fragments (vf) HOISTED out of the mi loop — address is
// mi-independent, but the GLOAD16 memory clobbers may have prevented the
// compiler from CSE-ing them (20 -> 8 ds_read_b128 per wave per round).
// Epilogue: 2-pass kh-combine through dead K/V LDS.
// XCD-local: XCD x owns (h,b) groups 4x..4x+3 -> 2 MB K/V set in its L2.
// ---------------------------------------------------------------------------
__global__ __launch_bounds__(512, 1) void attn10(
    const unsigned short* __restrict__ qk, const unsigned short* __restrict__ vt,
    unsigned short* __restrict__ ao) {
  __shared__ __attribute__((aligned(16))) unsigned short KV[6 * 4096];  // 48 KB
  unsigned short* Ksb = KV;             // [3][64*64]
  unsigned short* Vsb = KV + 3 * 4096;  // [3][64*64]

  const int tid = threadIdx.x;
  const int w = tid >> 6, lane = tid & 63, quad = lane >> 4, c = lane & 15;
  const int qh = w >> 1, kh = w & 1;
  const int L = blockIdx.x, x = L & 7, g = L >> 3;
  const int hb = x * 4 + (g >> 3);   // 4 (h,b) groups per XCD
  const int h = hb & 15, b = hb >> 4;
  const int q0 = (g & 7) * 256;      // 8 q-tiles of 256 rows
  const int rk = c & 7;

  short8_t qf[4][2];
  {
    const size_t rb = (size_t)b * SEQ + q0 + qh * 64;
#pragma unroll
    for (int mi = 0; mi < 4; ++mi) {
      const size_t qr = (rb + mi * 16 + c) * 2048 + h * 64 + quad * 8;
      qf[mi][0] = *(const short8_t*)&qk[qr];
      qf[mi][1] = *(const short8_t*)&qk[qr + 32];
    }
  }
  __asm__ __volatile__("s_waitcnt vmcnt(0)" ::: "memory");  // clean vmcnt queue

  floatx4 O[4][4], Osum[4];
  const floatx4 z = {0.f, 0.f, 0.f, 0.f};
#pragma unroll
  for (int mi = 0; mi < 4; ++mi) {
    Osum[mi] = z;
#pragma unroll
    for (int dg = 0; dg < 4; ++dg) O[mi][dg] = z;
  }
  short8_t ones;
#pragma unroll
  for (int e = 0; e < 8; ++e) ones[e] = (short)0x3F80;  // bf16 1.0

  const int srow = lane >> 3;           // 0..7
  const int sblkg = (lane & 7) ^ srow;  // staging chunk swizzle
  const unsigned short* gK = qk + (size_t)b * SEQ * 2048 + 1024 + h * 64;
  const unsigned short* gV = vt + (size_t)(b * 16 + h) * 64 * 2048;

  stage_kv16(w, srow, sblkg, gK, gV, Ksb, Vsb, 0);
  stage_kv16(w, srow, sblkg, gK, gV, Ksb + 4096, Vsb + 4096, 1);

  const int octv = ((4 * kh + quad) ^ rk) * 8;

  for (int t = 0; t < 32; ++t) {
    // counted wait: stage-t landed (2 oldest), stage-(t+1) stays in flight
    __asm__ __volatile__("s_waitcnt vmcnt(2)" ::: "memory");
    WGBAR();  // all waves: stage-t landed AND compute t-1 finished
    // wrap-around stage keeps vmcnt counts uniform (tiles 0,1 re-staged into
    // bufs that are never read again -- harmless, keeps the pipe full)
    stage_kv16(w, srow, sblkg, gK, gV, Ksb + ((t + 2) % 3) * 4096,
               Vsb + ((t + 2) % 3) * 4096, (t + 2) & 31);
    const unsigned short* Kc = Ksb + (t % 3) * 4096;
    const unsigned short* Vc = Vsb + (t % 3) * 4096;

    // S^T = K Q^T restricted to this wave's 32 keys:
    // lane = q, S[mi][jg][u] = key kh*32 + jg*16 + quad*4 + u
    floatx4 S[4][2];
#pragma unroll
    for (int mi = 0; mi < 4; ++mi)
#pragma unroll
      for (int jg = 0; jg < 2; ++jg) S[mi][jg] = z;
#pragma unroll
    for (int kd = 0; kd < 2; ++kd) {
      const int oct = ((4 * kd + quad) ^ rk) * 8;
#pragma unroll
      for (int jg = 0; jg < 2; ++jg) {
        short8_t kf = *(const short8_t*)&Kc[((kh * 2 + jg) * 16 + c) * 64 + oct];
#pragma unroll
        for (int mi = 0; mi < 4; ++mi)
          S[mi][jg] = __builtin_amdgcn_mfma_f32_16x16x32_bf16(kf, qf[mi][kd], S[mi][jg], 0, 0, 0);
      }
    }

    // V fragments hoisted: address is mi-independent -> load ONCE per round.
    short8_t vf[4];
#pragma unroll
    for (int dg = 0; dg < 4; ++dg)
      vf[dg] = *(const short8_t*)&Vc[(dg * 16 + c) * 64 + octv];

    // P = exp2(S^T) -> bf16 pairs, kept in registers; PV on this key half.
#pragma unroll
    for (int mi = 0; mi < 4; ++mi) {
      unsigned int pw[2][2];
#pragma unroll
      for (int jg = 0; jg < 2; ++jg) {
        float p0 = __builtin_amdgcn_exp2f(S[mi][jg][0]);
        float p1 = __builtin_amdgcn_exp2f(S[mi][jg][1]);
        float p2 = __builtin_amdgcn_exp2f(S[mi][jg][2]);
        float p3 = __builtin_amdgcn_exp2f(S[mi][jg][3]);
        pw[jg][0] = pack_bf(p0, p1);
        pw[jg][1] = pack_bf(p2, p3);
      }
      short8_t pb = mk_pb(pw[0][0], pw[0][1], pw[1][0], pw[1][1]);
      Osum[mi] = __builtin_amdgcn_mfma_f32_16x16x32_bf16(ones, pb, Osum[mi], 0, 0, 0);
#pragma unroll
      for (int dg = 0; dg < 4; ++dg)
        O[mi][dg] = __builtin_amdgcn_mfma_f32_16x16x32_bf16(vf[dg], pb, O[mi][dg], 0, 0, 0);
    }
  }

  __asm__ __volatile__("s_waitcnt vmcnt(0)" ::: "memory");  // drain trailing DMA
  WGBAR();  // all compute done -> K/V LDS reusable as f32 scratch

  // combine across key-halves, 2 passes of 128 q-rows through dead K/V LDS.
  // Of: [128][68] f32 (pad 68 breaks bank aliasing), Ss2: [128] f32.
  float* Of = (float*)KV;
  float* Ss2 = (float*)((char*)KV + 34816);
#pragma unroll
  for (int p = 0; p < 2; ++p) {
    if (kh == 1 && (qh >> 1) == p) {
#pragma unroll
      for (int mi = 0; mi < 4; ++mi) {
        const int row = (qh & 1) * 64 + mi * 16 + c;
        float* orow = &Of[row * 68];
#pragma unroll
        for (int dg = 0; dg < 4; ++dg)
          *(floatx4*)&orow[dg * 16 + quad * 4] = O[mi][dg];
        if (quad == 0) Ss2[row] = Osum[mi][0];
      }
    }
    WGBAR();
    if (kh == 0 && (qh >> 1) == p) {
#pragma unroll
      for (int mi = 0; mi < 4; ++mi) {
        const int row = (qh & 1) * 64 + mi * 16 + c;
        const float inv = 1.0f / (Osum[mi][0] + Ss2[row]);
        const float* orow = &Of[row * 68];
        const size_t grow = (size_t)b * SEQ + q0 + qh * 64 + mi * 16 + c;
#pragma unroll
        for (int dg = 0; dg < 4; ++dg) {
          floatx4 o = O[mi][dg] + *(const floatx4*)&orow[dg * 16 + quad * 4];
          ushort4_t ov = {f2bf(o[0] * inv), f2bf(o[1] * inv),
                          f2bf(o[2] * inv), f2bf(o[3] * inv)};
          *(ushort4_t*)&ao[grow * EMB + h * 64 + dg * 16 + quad * 4] = ov;
        }
      }
    }
    WGBAR();
  }
}

// ---------------------------------------------------------------------------
extern "C" void kernel_launch(void* const* d_in, const int* in_sizes, int n_in,
                              void* d_out, int out_size, void* d_ws, size_t ws_size,
                              hipStream_t stream) {
  const float* hs = (const float*)d_in[0];        // [B,S,E]
  const float* c_attn_w = (const float*)d_in[1];  // [E,3E]
  const float* c_attn_b = (const float*)d_in[2];  // [3E]
  const float* c_proj_w = (const float*)d_in[3];  // [E,E]
  const float* c_proj_b = (const float*)d_in[4];  // [E]
  float* out = (float*)d_out;                     // [B,S,E] fp32

  char* ws = (char*)d_ws;
  unsigned short* hsb = (unsigned short*)(ws + 0);         // 8.39 MB [B,S,E] bf16
  unsigned short* qk  = (unsigned short*)(ws + 8388608);   // 16.8 MB [B,S,2048]
  unsigned short* vt  = (unsigned short*)(ws + 25165824);  // 8.39 MB [B,H,D,S] (key-permuted per 64-tile)
  unsigned short* aob = (unsigned short*)(ws + 33554432);  // 8.39 MB [B,S,E] bf16
  unsigned short* w1t = (unsigned short*)(ws + 41943040);  // 6.29 MB [3072,1024]
  unsigned short* w2t = (unsigned short*)(ws + 48234496);  // 2.10 MB [1024,1024]

  // 1) fused prepass: hs->bf16, transpose+convert both weight matrices
  prep<<<5120, 256, 0, stream>>>(hs, c_attn_w, c_proj_w, hsb, w1t, w2t);
  // 2) QKV GEMM (BK=64, 16 rounds -- R10 win) -> qk + vt
  gemm_pl<0, 128><<<768, 256, 0, stream>>>(hsb, w1t, c_attn_b, nullptr, qk, vt);
  // 3) attention megablock (KVBLK=64, vf hoisted) -> aob bf16
  attn10<<<256, 512, 0, stream>>>(qk, vt, aob);
  // 4) output projection (BK=64, 16 rounds) -> fp32 out
  gemm_pl<2, 64><<<512, 256, 0, stream>>>(aob, w2t, c_proj_b, out, nullptr, nullptr);
}

// Round 15
// 169.122 us; speedup vs baseline: 1.2445x; 1.0266x over previous
//
#include <hip/hip_runtime.h>

// B=2, S=2048, E=1024, H=16, D=64
#define SEQ 2048
#define EMB 1024
#define KDIM 1024
#define CF 0.180336880111113f  // (1/sqrt(64)) * log2(e), folded into Q

typedef __attribute__((ext_vector_type(8))) short short8_t;
typedef __attribute__((ext_vector_type(4))) float floatx4;
typedef __attribute__((ext_vector_type(4))) unsigned short ushort4_t;
typedef __attribute__((ext_vector_type(4))) unsigned int uivec4;

#define GLOAD16(gp, lp)                                                        \
  __builtin_amdgcn_global_load_lds(                                            \
      (const __attribute__((address_space(1))) void*)(gp),                     \
      (__attribute__((address_space(3))) void*)(lp), 16, 0, 0)

#define WGBAR()                                   \
  do {                                            \
    __asm__ __volatile__("" ::: "memory");        \
    __builtin_amdgcn_s_barrier();                 \
    __asm__ __volatile__("" ::: "memory");        \
  } while (0)

static __device__ __forceinline__ unsigned short f2bf(float x) {
  unsigned int u = __float_as_uint(x);
  return (unsigned short)((u + 0x7fffu + ((u >> 16) & 1u)) >> 16);
}

static __device__ __forceinline__ short8_t mk_pb(unsigned int a, unsigned int b,
                                                 unsigned int c, unsigned int d) {
  uivec4 t;
  t[0] = a; t[1] = b; t[2] = c; t[3] = d;
  return __builtin_bit_cast(short8_t, t);
}

// pack bf16(trunc) pair: low = hi16(p0), high = hi16(p1), one v_perm_b32
static __device__ __forceinline__ unsigned int pack_bf(float p0, float p1) {
  return __builtin_amdgcn_perm(__float_as_uint(p1), __float_as_uint(p0),
                               0x07060302u);
}

// ---------------------------------------------------------------------------
// Fused prepass: blockIdx 0..4095   -> hs fp32 -> bf16
//                4096..4863         -> c_attn_w [1024,3072] -> w1t [3072,1024]
//                4864..5119         -> c_proj_w [1024,1024] -> w2t [1024,1024]
// ---------------------------------------------------------------------------
static __device__ __forceinline__ void tconv_tile(
    const float* __restrict__ W, unsigned short* __restrict__ T, int N, int K,
    int n0, int k0, int tid) {
  __shared__ float Tl[64][65];
  const int lx = tid & 15, ly = tid >> 4;
#pragma unroll
  for (int u = 0; u < 4; ++u) {
    int r = u * 16 + ly;
    float4 v = *(const float4*)&W[(size_t)(k0 + r) * N + n0 + lx * 4];
    Tl[r][lx * 4 + 0] = v.x;
    Tl[r][lx * 4 + 1] = v.y;
    Tl[r][lx * 4 + 2] = v.z;
    Tl[r][lx * 4 + 3] = v.w;
  }
  __syncthreads();
#pragma unroll
  for (int u = 0; u < 4; ++u) {
    int n = u * 16 + ly;
    ushort4_t h;
#pragma unroll
    for (int v = 0; v < 4; ++v) h[v] = f2bf(Tl[lx * 4 + v][n]);
    *(ushort4_t*)&T[(size_t)(n0 + n) * K + k0 + lx * 4] = h;
  }
}

__global__ __launch_bounds__(256) void prep(
    const float* __restrict__ hs, const float* __restrict__ caw,
    const float* __restrict__ cpw, unsigned short* __restrict__ hsb,
    unsigned short* __restrict__ w1t, unsigned short* __restrict__ w2t) {
  const int bid = blockIdx.x, tid = threadIdx.x;
  if (bid < 4096) {
    const int i = bid * 256 + tid;
    float4 v = *(const float4*)&hs[(size_t)i * 4];
    ushort4_t h = {f2bf(v.x), f2bf(v.y), f2bf(v.z), f2bf(v.w)};
    *(ushort4_t*)&hsb[(size_t)i * 4] = h;
  } else if (bid < 4864) {
    const int idx = bid - 4096;
    tconv_tile(caw, w1t, 3 * EMB, EMB, (idx % 48) * 64, (idx / 48) * 64, tid);
  } else {
    const int idx = bid - 4864;
    tconv_tile(cpw, w2t, EMB, EMB, (idx % 16) * 64, (idx / 16) * 64, tid);
  }
}

// ---------------------------------------------------------------------------
// bf16 MFMA GEMM, BK=64 -> 16 ROUNDS (R10-proven).  Double-buffered LDS,
// depth-1 prefetch, one barrier/round.  Rows are 128 B; staging uses the
// 8-row GLOAD16 pattern with (chunk ^ row&7) XOR swizzle.
// Tile 128 x BN.  A: [M,1024] bf16;  Bt: [N,1024] bf16 (W^T).
// MODE 0 (BN=192, 512 blocks, LDS 80 KB): R15 reshape — grid == exactly
//   2 blocks/CU residency -> single BALANCED pass (the 768-block version ran
//   512 + 256-with-half-CUs-idle).  cols<2048 -> qk (q scaled CF); else vt
//   (KEY-PERMUTED per 64-key tile -> attn consumes P from registers).
//   Tiles may straddle the qk/vt boundary: branches are per-4-col group, and
//   vt's 4-wide d-groups never cross a 64-key tile.
// MODE 2 (BN=64, 512 blocks, LDS 48 KB): fp32 out [M,1024].
// ---------------------------------------------------------------------------
template <int MODE, int BN>
__global__ __launch_bounds__(256, MODE == 0 ? 2 : 3) void gemm_pl(
    const unsigned short* __restrict__ Ag, const unsigned short* __restrict__ Bg,
    const float* __restrict__ bias, float* __restrict__ outF,
    unsigned short* __restrict__ qk, unsigned short* __restrict__ vt) {
  __shared__ __attribute__((aligned(16))) unsigned short Ah[2][128 * 64];
  __shared__ __attribute__((aligned(16))) unsigned short Bh[2][BN * 64];
  const int NJ = BN / 32;  // j-frag groups per wave

  const int tid = threadIdx.x;
  const int w = tid >> 6, lane = tid & 63;
  const int quad = lane >> 4, c = lane & 15;
  const int rk = c & 7;

  // XCD swizzle: rectangles per XCD sized to (mostly) fit the 4 MB L2
  int bm, bn;
  {
    const int L = blockIdx.x, x = L & 7, g = L >> 3;
    if (MODE == 0) {  // 512 blocks (32bm x 16bn): per-XCD 8bm x 8bn
      bm = ((x & 3) * 8 + (g & 7)) * 128;
      bn = ((x >> 2) * 8 + (g >> 3)) * 192;
    } else {  // 512 blocks: per-XCD 8bm x 8bn (A 2MB + B 1MB)
      bm = ((x & 3) * 8 + (g & 7)) * 128;
      bn = ((x >> 2) * 8 + (g >> 3)) * 64;
    }
  }
  const int wm = (w >> 1) * 64, wn = (w & 1) * (BN / 2);

  // staging: waves 0,1 -> A halves (64 rows, 8 GLOAD16); waves 2,3 -> B
  // halves (BN/2 rows, BN/16 GLOAD16).
  const unsigned short* gsrc = (w < 2) ? Ag : Bg;
  const int lbo = (w < 2) ? (w & 1) * 64 * 64 : (w & 1) * (BN / 2) * 64;
  const int rbase = (w < 2) ? (bm + (w & 1) * 64) : (bn + (w & 1) * (BN / 2));
  const int nloads = (w < 2) ? 8 : (BN / 16);
  const int srow = lane >> 3;           // 0..7
  const int sblkg = (lane & 7) ^ srow;  // XOR chunk swizzle (128 B rows)
  const char* gp0 = (const char*)(gsrc + (size_t)(rbase + srow) * KDIM) + sblkg * 16;

  floatx4 acc[4][NJ];
  const floatx4 z = {0.f, 0.f, 0.f, 0.f};
#pragma unroll
  for (int i = 0; i < 4; ++i)
#pragma unroll
    for (int j = 0; j < NJ; ++j) acc[i][j] = z;

#define STAGE_G(buf, kt)                                                       \
  do {                                                                         \
    unsigned short* ld = ((w < 2) ? Ah[buf] : Bh[buf]) + lbo;                  \
    const char* gp = gp0 + (size_t)(kt) * 128;                                 \
    for (int i_ = 0; i_ < nloads; ++i_)                                        \
      GLOAD16(gp + (size_t)i_ * 8 * (KDIM * 2), &ld[i_ * 512]);                \
  } while (0)

  STAGE_G(0, 0);

  for (int t = 0; t < 16; ++t) {
    __asm__ __volatile__("s_waitcnt vmcnt(0)" ::: "memory");  // stage-t landed
    WGBAR();  // all waves: stage-t landed AND compute t-1 finished
    if (t < 15) STAGE_G((t + 1) & 1, t + 1);  // overwrites buf read in t-1
    const unsigned short* Ac = Ah[t & 1];
    const unsigned short* Bc = Bh[t & 1];

#pragma unroll
    for (int kd = 0; kd < 2; ++kd) {
      const int oct = ((4 * kd + quad) ^ rk) * 8;
      short8_t a[4], b[NJ];
#pragma unroll
      for (int i = 0; i < 4; ++i)
        a[i] = *(const short8_t*)&Ac[(wm + 16 * i + c) * 64 + oct];
#pragma unroll
      for (int j = 0; j < NJ; ++j)
        b[j] = *(const short8_t*)&Bc[(wn + 16 * j + c) * 64 + oct];
      // transposed: lane = A-row (m), regs = 4 consecutive B-rows (n)
#pragma unroll
      for (int i = 0; i < 4; ++i)
#pragma unroll
        for (int j = 0; j < NJ; ++j)
          acc[i][j] = __builtin_amdgcn_mfma_f32_16x16x32_bf16(b[j], a[i], acc[i][j], 0, 0, 0);
    }
  }
#undef STAGE_G

#pragma unroll
  for (int i = 0; i < 4; ++i) {
    const int row = bm + wm + 16 * i + c;
#pragma unroll
    for (int j = 0; j < NJ; ++j) {
      const int col0 = bn + wn + 16 * j + quad * 4;
      floatx4 v = acc[i][j] + *(const floatx4*)&bias[col0];
      if (MODE == 0) {
        if (col0 < 1024) v = v * CF;
        if (col0 < 2048) {
          ushort4_t pk = {f2bf(v[0]), f2bf(v[1]), f2bf(v[2]), f2bf(v[3])};
          *(ushort4_t*)&qk[(size_t)row * 2048 + col0] = pk;
        } else {
          const int c2 = col0 - 2048, hh = c2 >> 6, d0 = c2 & 63;
          const int bb = row >> 11, s = row & 2047;
          // Key permutation within each 64-key tile so the attn PV MFMA can
          // use lane-local P registers as the B operand directly.
          // Logical slot lam (bits [kq][q1 q0][a][r1 r0]) holds global key
          // j (bits [kq][a][q1 q0][r1 r0]):  lam = invpi(j).
          const int j = s & 63;
          const int lam = (j & 0x20) | ((j & 0x0C) << 1) | ((j & 0x10) >> 2) | (j & 3);
          const int sp = (s & ~63) | lam;
          unsigned short* vb = &vt[((size_t)(bb * 16 + hh) * 64 + d0) * 2048 + sp];
          vb[0 * 2048] = f2bf(v[0]);
          vb[1 * 2048] = f2bf(v[1]);
          vb[2 * 2048] = f2bf(v[2]);
          vb[3 * 2048] = f2bf(v[3]);
        }
      } else {
        *(floatx4*)&outF[(size_t)row * 1024 + col0] = v;
      }
    }
  }
}

// ---------------------------------------------------------------------------
// K/V staging for the megablock: 8 waves, 16 rows each, 2 GLOAD16/wave.
// waves 0..3 -> K rows w*16..+15; waves 4..7 -> V^T d-rows (w-4)*16..+15.
// ---------------------------------------------------------------------------
static __device__ __forceinline__ void stage_kv16(
    int w, int srow, int sblkg, const unsigned short* __restrict__ gK,
    const unsigned short* __restrict__ gV, unsigned short* Kbuf,
    unsigned short* Vbuf, int jt) {
  if (w < 4) {
    const unsigned short* g0 =
        gK + (size_t)(jt * 64 + w * 16 + srow) * 2048 + sblkg * 8;
    unsigned short* l0 = &Kbuf[(w * 16) * 64];
    GLOAD16(g0, l0);
    GLOAD16(g0 + (size_t)8 * 2048, l0 + 8 * 64);
  } else {
    const unsigned short* g0 =
        gV + (size_t)((w - 4) * 16 + srow) * 2048 + jt * 64 + sblkg * 8;
    unsigned short* l0 = &Vbuf[((w - 4) * 16) * 64];
    GLOAD16(g0, l0);
    GLOAD16(g0 + (size_t)8 * 2048, l0 + 8 * 64);
  }
}

// ---------------------------------------------------------------------------
// bf16 MFMA flash attention MEGABLOCK (measured best: 43.2 us, R14):
// 256 blocks x 512 thr = 1 block/CU; q-tile 256 rows; waves = 4 qh x 2 kh;
// KVBLK=64; triple-buffered K/V, counted vmcnt(2), wrap-around staging;
// in-register P via vt key-permutation; fixed-max softmax; V fragments
// hoisted out of the mi loop (R14 win: compiler wasn't CSE-ing past the
// GLOAD16 clobbers — 20 -> 8 ds_read_b128/wave/round).
// Epilogue: 2-pass kh-combine through dead K/V LDS.
// XCD-local: XCD x owns (h,b) groups 4x..4x+3 -> 2 MB K/V set in its L2.
// ---------------------------------------------------------------------------
__global__ __launch_bounds__(512, 1) void attn10(
    const unsigned short* __restrict__ qk, const unsigned short* __restrict__ vt,
    unsigned short* __restrict__ ao) {
  __shared__ __attribute__((aligned(16))) unsigned short KV[6 * 4096];  // 48 KB
  unsigned short* Ksb = KV;             // [3][64*64]
  unsigned short* Vsb = KV + 3 * 4096;  // [3][64*64]

  const int tid = threadIdx.x;
  const int w = tid >> 6, lane = tid & 63, quad = lane >> 4, c = lane & 15;
  const int qh = w >> 1, kh = w & 1;
  const int L = blockIdx.x, x = L & 7, g = L >> 3;
  const int hb = x * 4 + (g >> 3);   // 4 (h,b) groups per XCD
  const int h = hb & 15, b = hb >> 4;
  const int q0 = (g & 7) * 256;      // 8 q-tiles of 256 rows
  const int rk = c & 7;

  short8_t qf[4][2];
  {
    const size_t rb = (size_t)b * SEQ + q0 + qh * 64;
#pragma unroll
    for (int mi = 0; mi < 4; ++mi) {
      const size_t qr = (rb + mi * 16 + c) * 2048 + h * 64 + quad * 8;
      qf[mi][0] = *(const short8_t*)&qk[qr];
      qf[mi][1] = *(const short8_t*)&qk[qr + 32];
    }
  }
  __asm__ __volatile__("s_waitcnt vmcnt(0)" ::: "memory");  // clean vmcnt queue

  floatx4 O[4][4], Osum[4];
  const floatx4 z = {0.f, 0.f, 0.f, 0.f};
#pragma unroll
  for (int mi = 0; mi < 4; ++mi) {
    Osum[mi] = z;
#pragma unroll
    for (int dg = 0; dg < 4; ++dg) O[mi][dg] = z;
  }
  short8_t ones;
#pragma unroll
  for (int e = 0; e < 8; ++e) ones[e] = (short)0x3F80;  // bf16 1.0

  const int srow = lane >> 3;           // 0..7
  const int sblkg = (lane & 7) ^ srow;  // staging chunk swizzle
  const unsigned short* gK = qk + (size_t)b * SEQ * 2048 + 1024 + h * 64;
  const unsigned short* gV = vt + (size_t)(b * 16 + h) * 64 * 2048;

  stage_kv16(w, srow, sblkg, gK, gV, Ksb, Vsb, 0);
  stage_kv16(w, srow, sblkg, gK, gV, Ksb + 4096, Vsb + 4096, 1);

  const int octv = ((4 * kh + quad) ^ rk) * 8;

  for (int t = 0; t < 32; ++t) {
    // counted wait: stage-t landed (2 oldest), stage-(t+1) stays in flight
    __asm__ __volatile__("s_waitcnt vmcnt(2)" ::: "memory");
    WGBAR();  // all waves: stage-t landed AND compute t-1 finished
    // wrap-around stage keeps vmcnt counts uniform (tiles 0,1 re-staged into
    // bufs that are never read again -- harmless, keeps the pipe full)
    stage_kv16(w, srow, sblkg, gK, gV, Ksb + ((t + 2) % 3) * 4096,
               Vsb + ((t + 2) % 3) * 4096, (t + 2) & 31);
    const unsigned short* Kc = Ksb + (t % 3) * 4096;
    const unsigned short* Vc = Vsb + (t % 3) * 4096;

    // S^T = K Q^T restricted to this wave's 32 keys:
    // lane = q, S[mi][jg][u] = key kh*32 + jg*16 + quad*4 + u
    floatx4 S[4][2];
#pragma unroll
    for (int mi = 0; mi < 4; ++mi)
#pragma unroll
      for (int jg = 0; jg < 2; ++jg) S[mi][jg] = z;
#pragma unroll
    for (int kd = 0; kd < 2; ++kd) {
      const int oct = ((4 * kd + quad) ^ rk) * 8;
#pragma unroll
      for (int jg = 0; jg < 2; ++jg) {
        short8_t kf = *(const short8_t*)&Kc[((kh * 2 + jg) * 16 + c) * 64 + oct];
#pragma unroll
        for (int mi = 0; mi < 4; ++mi)
          S[mi][jg] = __builtin_amdgcn_mfma_f32_16x16x32_bf16(kf, qf[mi][kd], S[mi][jg], 0, 0, 0);
      }
    }

    // V fragments hoisted: address is mi-independent -> load ONCE per round.
    short8_t vf[4];
#pragma unroll
    for (int dg = 0; dg < 4; ++dg)
      vf[dg] = *(const short8_t*)&Vc[(dg * 16 + c) * 64 + octv];

    // P = exp2(S^T) -> bf16 pairs, kept in registers; PV on this key half.
#pragma unroll
    for (int mi = 0; mi < 4; ++mi) {
      unsigned int pw[2][2];
#pragma unroll
      for (int jg = 0; jg < 2; ++jg) {
        float p0 = __builtin_amdgcn_exp2f(S[mi][jg][0]);
        float p1 = __builtin_amdgcn_exp2f(S[mi][jg][1]);
        float p2 = __builtin_amdgcn_exp2f(S[mi][jg][2]);
        float p3 = __builtin_amdgcn_exp2f(S[mi][jg][3]);
        pw[jg][0] = pack_bf(p0, p1);
        pw[jg][1] = pack_bf(p2, p3);
      }
      short8_t pb = mk_pb(pw[0][0], pw[0][1], pw[1][0], pw[1][1]);
      Osum[mi] = __builtin_amdgcn_mfma_f32_16x16x32_bf16(ones, pb, Osum[mi], 0, 0, 0);
#pragma unroll
      for (int dg = 0; dg < 4; ++dg)
        O[mi][dg] = __builtin_amdgcn_mfma_f32_16x16x32_bf16(vf[dg], pb, O[mi][dg], 0, 0, 0);
    }
  }

  __asm__ __volatile__("s_waitcnt vmcnt(0)" ::: "memory");  // drain trailing DMA
  WGBAR();  // all compute done -> K/V LDS reusable as f32 scratch

  // combine across key-halves, 2 passes of 128 q-rows through dead K/V LDS.
  // Of: [128][68] f32 (pad 68 breaks bank aliasing), Ss2: [128] f32.
  float* Of = (float*)KV;
  float* Ss2 = (float*)((char*)KV + 34816);
#pragma unroll
  for (int p = 0; p < 2; ++p) {
    if (kh == 1 && (qh >> 1) == p) {
#pragma unroll
      for (int mi = 0; mi < 4; ++mi) {
        const int row = (qh & 1) * 64 + mi * 16 + c;
        float* orow = &Of[row * 68];
#pragma unroll
        for (int dg = 0; dg < 4; ++dg)
          *(floatx4*)&orow[dg * 16 + quad * 4] = O[mi][dg];
        if (quad == 0) Ss2[row] = Osum[mi][0];
      }
    }
    WGBAR();
    if (kh == 0 && (qh >> 1) == p) {
#pragma unroll
      for (int mi = 0; mi < 4; ++mi) {
        const int row = (qh & 1) * 64 + mi * 16 + c;
        const float inv = 1.0f / (Osum[mi][0] + Ss2[row]);
        const float* orow = &Of[row * 68];
        const size_t grow = (size_t)b * SEQ + q0 + qh * 64 + mi * 16 + c;
#pragma unroll
        for (int dg = 0; dg < 4; ++dg) {
          floatx4 o = O[mi][dg] + *(const floatx4*)&orow[dg * 16 + quad * 4];
          ushort4_t ov = {f2bf(o[0] * inv), f2bf(o[1] * inv),
                          f2bf(o[2] * inv), f2bf(o[3] * inv)};
          *(ushort4_t*)&ao[grow * EMB + h * 64 + dg * 16 + quad * 4] = ov;
        }
      }
    }
    WGBAR();
  }
}

// ---------------------------------------------------------------------------
extern "C" void kernel_launch(void* const* d_in, const int* in_sizes, int n_in,
                              void* d_out, int out_size, void* d_ws, size_t ws_size,
                              hipStream_t stream) {
  const float* hs = (const float*)d_in[0];        // [B,S,E]
  const float* c_attn_w = (const float*)d_in[1];  // [E,3E]
  const float* c_attn_b = (const float*)d_in[2];  // [3E]
  const float* c_proj_w = (const float*)d_in[3];  // [E,E]
  const float* c_proj_b = (const float*)d_in[4];  // [E]
  float* out = (float*)d_out;                     // [B,S,E] fp32

  char* ws = (char*)d_ws;
  unsigned short* hsb = (unsigned short*)(ws + 0);         // 8.39 MB [B,S,E] bf16
  unsigned short* qk  = (unsigned short*)(ws + 8388608);   // 16.8 MB [B,S,2048]
  unsigned short* vt  = (unsigned short*)(ws + 25165824);  // 8.39 MB [B,H,D,S] (key-permuted per 64-tile)
  unsigned short* aob = (unsigned short*)(ws + 33554432);  // 8.39 MB [B,S,E] bf16
  unsigned short* w1t = (unsigned short*)(ws + 41943040);  // 6.29 MB [3072,1024]
  unsigned short* w2t = (unsigned short*)(ws + 48234496);  // 2.10 MB [1024,1024]

  // 1) fused prepass: hs->bf16, transpose+convert both weight matrices
  prep<<<5120, 256, 0, stream>>>(hs, c_attn_w, c_proj_w, hsb, w1t, w2t);
  // 2) QKV GEMM (128x192 tiles, 512 blocks = exactly 2/CU, balanced) -> qk + vt
  gemm_pl<0, 192><<<512, 256, 0, stream>>>(hsb, w1t, c_attn_b, nullptr, qk, vt);
  // 3) attention megablock (KVBLK=64, vf hoisted, 43.2 us) -> aob bf16
  attn10<<<256, 512, 0, stream>>>(qk, vt, aob);
  // 4) output projection (BK=64, 16 rounds) -> fp32 out
  gemm_pl<2, 64><<<512, 256, 0, stream>>>(aob, w2t, c_proj_b, out, nullptr, nullptr);
}

// Round 16
// 166.151 us; speedup vs baseline: 1.2668x; 1.0179x over previous
//
#include <hip/hip_runtime.h>

// B=2, S=2048, E=1024, H=16, D=64
#define SEQ 2048
#define EMB 1024
#define KDIM 1024
#define CF 0.180336880111113f  // (1/sqrt(64)) * log2(e), folded into Q

typedef __attribute__((ext_vector_type(8))) short short8_t;
typedef __attribute__((ext_vector_type(4))) float floatx4;
typedef __attribute__((ext_vector_type(4))) unsigned short ushort4_t;
typedef __attribute__((ext_vector_type(4))) unsigned int uivec4;

#define GLOAD16(gp, lp)                                                        \
  __builtin_amdgcn_global_load_lds(                                            \
      (const __attribute__((address_space(1))) void*)(gp),                     \
      (__attribute__((address_space(3))) void*)(lp), 16, 0, 0)

#define WGBAR()                                   \
  do {                                            \
    __asm__ __volatile__("" ::: "memory");        \
    __builtin_amdgcn_s_barrier();                 \
    __asm__ __volatile__("" ::: "memory");        \
  } while (0)

static __device__ __forceinline__ unsigned short f2bf(float x) {
  unsigned int u = __float_as_uint(x);
  return (unsigned short)((u + 0x7fffu + ((u >> 16) & 1u)) >> 16);
}

static __device__ __forceinline__ short8_t mk_pb(unsigned int a, unsigned int b,
                                                 unsigned int c, unsigned int d) {
  uivec4 t;
  t[0] = a; t[1] = b; t[2] = c; t[3] = d;
  return __builtin_bit_cast(short8_t, t);
}

// pack bf16(trunc) pair: low = hi16(p0), high = hi16(p1), one v_perm_b32
static __device__ __forceinline__ unsigned int pack_bf(float p0, float p1) {
  return __builtin_amdgcn_perm(__float_as_uint(p1), __float_as_uint(p0),
                               0x07060302u);
}

// ---------------------------------------------------------------------------
// Fused prepass: blockIdx 0..4095   -> hs fp32 -> bf16
//                4096..4863         -> c_attn_w [1024,3072] -> w1t [3072,1024]
//                4864..5119         -> c_proj_w [1024,1024] -> w2t [1024,1024]
// ---------------------------------------------------------------------------
static __device__ __forceinline__ void tconv_tile(
    const float* __restrict__ W, unsigned short* __restrict__ T, int N, int K,
    int n0, int k0, int tid) {
  __shared__ float Tl[64][65];
  const int lx = tid & 15, ly = tid >> 4;
#pragma unroll
  for (int u = 0; u < 4; ++u) {
    int r = u * 16 + ly;
    float4 v = *(const float4*)&W[(size_t)(k0 + r) * N + n0 + lx * 4];
    Tl[r][lx * 4 + 0] = v.x;
    Tl[r][lx * 4 + 1] = v.y;
    Tl[r][lx * 4 + 2] = v.z;
    Tl[r][lx * 4 + 3] = v.w;
  }
  __syncthreads();
#pragma unroll
  for (int u = 0; u < 4; ++u) {
    int n = u * 16 + ly;
    ushort4_t h;
#pragma unroll
    for (int v = 0; v < 4; ++v) h[v] = f2bf(Tl[lx * 4 + v][n]);
    *(ushort4_t*)&T[(size_t)(n0 + n) * K + k0 + lx * 4] = h;
  }
}

__global__ __launch_bounds__(256) void prep(
    const float* __restrict__ hs, const float* __restrict__ caw,
    const float* __restrict__ cpw, unsigned short* __restrict__ hsb,
    unsigned short* __restrict__ w1t, unsigned short* __restrict__ w2t) {
  const int bid = blockIdx.x, tid = threadIdx.x;
  if (bid < 4096) {
    const int i = bid * 256 + tid;
    float4 v = *(const float4*)&hs[(size_t)i * 4];
    ushort4_t h = {f2bf(v.x), f2bf(v.y), f2bf(v.z), f2bf(v.w)};
    *(ushort4_t*)&hsb[(size_t)i * 4] = h;
  } else if (bid < 4864) {
    const int idx = bid - 4096;
    tconv_tile(caw, w1t, 3 * EMB, EMB, (idx % 48) * 64, (idx / 48) * 64, tid);
  } else {
    const int idx = bid - 4864;
    tconv_tile(cpw, w2t, EMB, EMB, (idx % 16) * 64, (idx / 16) * 64, tid);
  }
}

// ---------------------------------------------------------------------------
// bf16 MFMA GEMM, BK=64 -> 16 ROUNDS (R10-proven).  Double-buffered LDS,
// depth-1 prefetch, one barrier/round.  Rows are 128 B; staging uses the
// 8-row GLOAD16 pattern with (chunk ^ row&7) XOR swizzle.
// Tile 128 x BN.  A: [M,1024] bf16;  Bt: [N,1024] bf16 (W^T).
// MODE 0 (BN=192, 512 blocks, LDS 80 KB): exactly 2 blocks/CU, balanced.
//   cols<2048 -> qk (q scaled CF); else vt (KEY-PERMUTED per 64-key tile).
// MODE 2 (BN=64, 512 blocks, LDS 48 KB): fp32 out [M,1024].
// ---------------------------------------------------------------------------
template <int MODE, int BN>
__global__ __launch_bounds__(256, MODE == 0 ? 2 : 3) void gemm_pl(
    const unsigned short* __restrict__ Ag, const unsigned short* __restrict__ Bg,
    const float* __restrict__ bias, float* __restrict__ outF,
    unsigned short* __restrict__ qk, unsigned short* __restrict__ vt) {
  __shared__ __attribute__((aligned(16))) unsigned short Ah[2][128 * 64];
  __shared__ __attribute__((aligned(16))) unsigned short Bh[2][BN * 64];
  const int NJ = BN / 32;  // j-frag groups per wave

  const int tid = threadIdx.x;
  const int w = tid >> 6, lane = tid & 63;
  const int quad = lane >> 4, c = lane & 15;
  const int rk = c & 7;

  // XCD swizzle: rectangles per XCD sized to (mostly) fit the 4 MB L2
  int bm, bn;
  {
    const int L = blockIdx.x, x = L & 7, g = L >> 3;
    if (MODE == 0) {  // 512 blocks (32bm x 16bn): per-XCD 8bm x 8bn
      bm = ((x & 3) * 8 + (g & 7)) * 128;
      bn = ((x >> 2) * 8 + (g >> 3)) * 192;
    } else {  // 512 blocks: per-XCD 8bm x 8bn (A 2MB + B 1MB)
      bm = ((x & 3) * 8 + (g & 7)) * 128;
      bn = ((x >> 2) * 8 + (g >> 3)) * 64;
    }
  }
  const int wm = (w >> 1) * 64, wn = (w & 1) * (BN / 2);

  // staging: waves 0,1 -> A halves (64 rows, 8 GLOAD16); waves 2,3 -> B
  // halves (BN/2 rows, BN/16 GLOAD16).
  const unsigned short* gsrc = (w < 2) ? Ag : Bg;
  const int lbo = (w < 2) ? (w & 1) * 64 * 64 : (w & 1) * (BN / 2) * 64;
  const int rbase = (w < 2) ? (bm + (w & 1) * 64) : (bn + (w & 1) * (BN / 2));
  const int nloads = (w < 2) ? 8 : (BN / 16);
  const int srow = lane >> 3;           // 0..7
  const int sblkg = (lane & 7) ^ srow;  // XOR chunk swizzle (128 B rows)
  const char* gp0 = (const char*)(gsrc + (size_t)(rbase + srow) * KDIM) + sblkg * 16;

  floatx4 acc[4][NJ];
  const floatx4 z = {0.f, 0.f, 0.f, 0.f};
#pragma unroll
  for (int i = 0; i < 4; ++i)
#pragma unroll
    for (int j = 0; j < NJ; ++j) acc[i][j] = z;

#define STAGE_G(buf, kt)                                                       \
  do {                                                                         \
    unsigned short* ld = ((w < 2) ? Ah[buf] : Bh[buf]) + lbo;                  \
    const char* gp = gp0 + (size_t)(kt) * 128;                                 \
    for (int i_ = 0; i_ < nloads; ++i_)                                        \
      GLOAD16(gp + (size_t)i_ * 8 * (KDIM * 2), &ld[i_ * 512]);                \
  } while (0)

  STAGE_G(0, 0);

  for (int t = 0; t < 16; ++t) {
    __asm__ __volatile__("s_waitcnt vmcnt(0)" ::: "memory");  // stage-t landed
    WGBAR();  // all waves: stage-t landed AND compute t-1 finished
    if (t < 15) STAGE_G((t + 1) & 1, t + 1);  // overwrites buf read in t-1
    const unsigned short* Ac = Ah[t & 1];
    const unsigned short* Bc = Bh[t & 1];

#pragma unroll
    for (int kd = 0; kd < 2; ++kd) {
      const int oct = ((4 * kd + quad) ^ rk) * 8;
      short8_t a[4], b[NJ];
#pragma unroll
      for (int i = 0; i < 4; ++i)
        a[i] = *(const short8_t*)&Ac[(wm + 16 * i + c) * 64 + oct];
#pragma unroll
      for (int j = 0; j < NJ; ++j)
        b[j] = *(const short8_t*)&Bc[(wn + 16 * j + c) * 64 + oct];
      // transposed: lane = A-row (m), regs = 4 consecutive B-rows (n)
#pragma unroll
      for (int i = 0; i < 4; ++i)
#pragma unroll
        for (int j = 0; j < NJ; ++j)
          acc[i][j] = __builtin_amdgcn_mfma_f32_16x16x32_bf16(b[j], a[i], acc[i][j], 0, 0, 0);
    }
  }
#undef STAGE_G

#pragma unroll
  for (int i = 0; i < 4; ++i) {
    const int row = bm + wm + 16 * i + c;
#pragma unroll
    for (int j = 0; j < NJ; ++j) {
      const int col0 = bn + wn + 16 * j + quad * 4;
      floatx4 v = acc[i][j] + *(const floatx4*)&bias[col0];
      if (MODE == 0) {
        if (col0 < 1024) v = v * CF;
        if (col0 < 2048) {
          ushort4_t pk = {f2bf(v[0]), f2bf(v[1]), f2bf(v[2]), f2bf(v[3])};
          *(ushort4_t*)&qk[(size_t)row * 2048 + col0] = pk;
        } else {
          const int c2 = col0 - 2048, hh = c2 >> 6, d0 = c2 & 63;
          const int bb = row >> 11, s = row & 2047;
          // Key permutation within each 64-key tile so the attn PV MFMA can
          // use lane-local P registers as the B operand directly.
          // Logical slot lam (bits [kq][q1 q0][a][r1 r0]) holds global key
          // j (bits [kq][a][q1 q0][r1 r0]):  lam = invpi(j).
          const int j = s & 63;
          const int lam = (j & 0x20) | ((j & 0x0C) << 1) | ((j & 0x10) >> 2) | (j & 3);
          const int sp = (s & ~63) | lam;
          unsigned short* vb = &vt[((size_t)(bb * 16 + hh) * 64 + d0) * 2048 + sp];
          vb[0 * 2048] = f2bf(v[0]);
          vb[1 * 2048] = f2bf(v[1]);
          vb[2 * 2048] = f2bf(v[2]);
          vb[3 * 2048] = f2bf(v[3]);
        }
      } else {
        *(floatx4*)&outF[(size_t)row * 1024 + col0] = v;
      }
    }
  }
}

// ---------------------------------------------------------------------------
// K/V staging for the 1024-thr megablock: 16 waves, 8 rows each, 1 GLOAD16.
// waves 0..7 -> K rows w*8..+7; waves 8..15 -> V^T d-rows (w-8)*8..+7.
// ---------------------------------------------------------------------------
static __device__ __forceinline__ void stage_kv8(
    int w, int srow, int sblkg, const unsigned short* __restrict__ gK,
    const unsigned short* __restrict__ gV, unsigned short* Kbuf,
    unsigned short* Vbuf, int jt) {
  if (w < 8) {
    const unsigned short* g0 =
        gK + (size_t)(jt * 64 + w * 8 + srow) * 2048 + sblkg * 8;
    GLOAD16(g0, &Kbuf[(w * 8) * 64]);
  } else {
    const unsigned short* g0 =
        gV + (size_t)((w - 8) * 8 + srow) * 2048 + jt * 64 + sblkg * 8;
    GLOAD16(g0, &Vbuf[((w - 8) * 8) * 64]);
  }
}

// ---------------------------------------------------------------------------
// bf16 MFMA flash attention, 1024-THREAD MEGABLOCK (the R15 experiment:
// attn8 showed 4 waves/SIMD + 4x-redundant staging ~= attn10's 2 waves/SIMD
// + dedup'd staging.  This takes BOTH: 16 waves/CU (4/SIMD) at the SAME
// dedup'd 16 KB/CU/round staging — only the wave decomposition changes).
// 256 blocks x 1024 thr = 1 block/CU; q-tile 256 rows; waves = 8 qh x 2 kh
// (32 q-rows/wave, mi=2); KVBLK=64; triple-buffered K/V, counted vmcnt(1)
// (1 GLOAD16/wave/round), wrap-around staging; in-register P via vt
// key-permutation; fixed-max softmax; V fragments hoisted (R14 win).
// Epilogue: 2-pass kh-combine through dead K/V LDS (128 rows/pass).
// XCD-local: XCD x owns (h,b) groups 4x..4x+3 -> 2 MB K/V set in its L2.
// ---------------------------------------------------------------------------
__global__ __launch_bounds__(1024, 1) void attn13(
    const unsigned short* __restrict__ qk, const unsigned short* __restrict__ vt,
    unsigned short* __restrict__ ao) {
  __shared__ __attribute__((aligned(16))) unsigned short KV[6 * 4096];  // 48 KB
  unsigned short* Ksb = KV;             // [3][64*64]
  unsigned short* Vsb = KV + 3 * 4096;  // [3][64*64]

  const int tid = threadIdx.x;
  const int w = tid >> 6, lane = tid & 63, quad = lane >> 4, c = lane & 15;
  const int qh = w >> 1, kh = w & 1;    // qh 0..7, kh 0..1
  const int L = blockIdx.x, x = L & 7, g = L >> 3;
  const int hb = x * 4 + (g >> 3);   // 4 (h,b) groups per XCD
  const int h = hb & 15, b = hb >> 4;
  const int q0 = (g & 7) * 256;      // 8 q-tiles of 256 rows
  const int rk = c & 7;

  short8_t qf[2][2];
  {
    const size_t rb = (size_t)b * SEQ + q0 + qh * 32;
#pragma unroll
    for (int mi = 0; mi < 2; ++mi) {
      const size_t qr = (rb + mi * 16 + c) * 2048 + h * 64 + quad * 8;
      qf[mi][0] = *(const short8_t*)&qk[qr];
      qf[mi][1] = *(const short8_t*)&qk[qr + 32];
    }
  }
  __asm__ __volatile__("s_waitcnt vmcnt(0)" ::: "memory");  // clean vmcnt queue

  floatx4 O[2][4], Osum[2];
  const floatx4 z = {0.f, 0.f, 0.f, 0.f};
#pragma unroll
  for (int mi = 0; mi < 2; ++mi) {
    Osum[mi] = z;
#pragma unroll
    for (int dg = 0; dg < 4; ++dg) O[mi][dg] = z;
  }
  short8_t ones;
#pragma unroll
  for (int e = 0; e < 8; ++e) ones[e] = (short)0x3F80;  // bf16 1.0

  const int srow = lane >> 3;           // 0..7
  const int sblkg = (lane & 7) ^ srow;  // staging chunk swizzle
  const unsigned short* gK = qk + (size_t)b * SEQ * 2048 + 1024 + h * 64;
  const unsigned short* gV = vt + (size_t)(b * 16 + h) * 64 * 2048;

  stage_kv8(w, srow, sblkg, gK, gV, Ksb, Vsb, 0);
  stage_kv8(w, srow, sblkg, gK, gV, Ksb + 4096, Vsb + 4096, 1);

  const int octv = ((4 * kh + quad) ^ rk) * 8;

  for (int t = 0; t < 32; ++t) {
    // counted wait: stage-t landed (1 oldest), stage-(t+1) stays in flight
    __asm__ __volatile__("s_waitcnt vmcnt(1)" ::: "memory");
    WGBAR();  // all waves: stage-t landed AND compute t-1 finished
    // wrap-around stage keeps vmcnt counts uniform (tiles 0,1 re-staged into
    // bufs that are never read again -- harmless, keeps the pipe full)
    stage_kv8(w, srow, sblkg, gK, gV, Ksb + ((t + 2) % 3) * 4096,
              Vsb + ((t + 2) % 3) * 4096, (t + 2) & 31);
    const unsigned short* Kc = Ksb + (t % 3) * 4096;
    const unsigned short* Vc = Vsb + (t % 3) * 4096;

    // S^T = K Q^T restricted to this wave's 32 keys:
    // lane = q, S[mi][jg][u] = key kh*32 + jg*16 + quad*4 + u
    floatx4 S[2][2];
#pragma unroll
    for (int mi = 0; mi < 2; ++mi)
#pragma unroll
      for (int jg = 0; jg < 2; ++jg) S[mi][jg] = z;
#pragma unroll
    for (int kd = 0; kd < 2; ++kd) {
      const int oct = ((4 * kd + quad) ^ rk) * 8;
#pragma unroll
      for (int jg = 0; jg < 2; ++jg) {
        short8_t kf = *(const short8_t*)&Kc[((kh * 2 + jg) * 16 + c) * 64 + oct];
#pragma unroll
        for (int mi = 0; mi < 2; ++mi)
          S[mi][jg] = __builtin_amdgcn_mfma_f32_16x16x32_bf16(kf, qf[mi][kd], S[mi][jg], 0, 0, 0);
      }
    }

    // V fragments hoisted: address is mi-independent -> load ONCE per round.
    short8_t vf[4];
#pragma unroll
    for (int dg = 0; dg < 4; ++dg)
      vf[dg] = *(const short8_t*)&Vc[(dg * 16 + c) * 64 + octv];

    // P = exp2(S^T) -> bf16 pairs, kept in registers; PV on this key half.
#pragma unroll
    for (int mi = 0; mi < 2; ++mi) {
      unsigned int pw[2][2];
#pragma unroll
      for (int jg = 0; jg < 2; ++jg) {
        float p0 = __builtin_amdgcn_exp2f(S[mi][jg][0]);
        float p1 = __builtin_amdgcn_exp2f(S[mi][jg][1]);
        float p2 = __builtin_amdgcn_exp2f(S[mi][jg][2]);
        float p3 = __builtin_amdgcn_exp2f(S[mi][jg][3]);
        pw[jg][0] = pack_bf(p0, p1);
        pw[jg][1] = pack_bf(p2, p3);
      }
      short8_t pb = mk_pb(pw[0][0], pw[0][1], pw[1][0], pw[1][1]);
      Osum[mi] = __builtin_amdgcn_mfma_f32_16x16x32_bf16(ones, pb, Osum[mi], 0, 0, 0);
#pragma unroll
      for (int dg = 0; dg < 4; ++dg)
        O[mi][dg] = __builtin_amdgcn_mfma_f32_16x16x32_bf16(vf[dg], pb, O[mi][dg], 0, 0, 0);
    }
  }

  __asm__ __volatile__("s_waitcnt vmcnt(0)" ::: "memory");  // drain trailing DMA
  WGBAR();  // all compute done -> K/V LDS reusable as f32 scratch

  // combine across key-halves, 2 passes of 128 q-rows through dead K/V LDS.
  // Of: [128][68] f32 (pad 68 breaks bank aliasing), Ss2: [128] f32.
  // Pass p covers qh 4p..4p+3; row-in-pass = (qh&3)*32 + mi*16 + c.
  float* Of = (float*)KV;
  float* Ss2 = (float*)((char*)KV + 34816);
#pragma unroll
  for (int p = 0; p < 2; ++p) {
    if (kh == 1 && (qh >> 2) == p) {
#pragma unroll
      for (int mi = 0; mi < 2; ++mi) {
        const int row = (qh & 3) * 32 + mi * 16 + c;
        float* orow = &Of[row * 68];
#pragma unroll
        for (int dg = 0; dg < 4; ++dg)
          *(floatx4*)&orow[dg * 16 + quad * 4] = O[mi][dg];
        if (quad == 0) Ss2[row] = Osum[mi][0];
      }
    }
    WGBAR();
    if (kh == 0 && (qh >> 2) == p) {
#pragma unroll
      for (int mi = 0; mi < 2; ++mi) {
        const int row = (qh & 3) * 32 + mi * 16 + c;
        const float inv = 1.0f / (Osum[mi][0] + Ss2[row]);
        const float* orow = &Of[row * 68];
        const size_t grow = (size_t)b * SEQ + q0 + qh * 32 + mi * 16 + c;
#pragma unroll
        for (int dg = 0; dg < 4; ++dg) {
          floatx4 o = O[mi][dg] + *(const floatx4*)&orow[dg * 16 + quad * 4];
          ushort4_t ov = {f2bf(o[0] * inv), f2bf(o[1] * inv),
                          f2bf(o[2] * inv), f2bf(o[3] * inv)};
          *(ushort4_t*)&ao[grow * EMB + h * 64 + dg * 16 + quad * 4] = ov;
        }
      }
    }
    WGBAR();
  }
}

// ---------------------------------------------------------------------------
extern "C" void kernel_launch(void* const* d_in, const int* in_sizes, int n_in,
                              void* d_out, int out_size, void* d_ws, size_t ws_size,
                              hipStream_t stream) {
  const float* hs = (const float*)d_in[0];        // [B,S,E]
  const float* c_attn_w = (const float*)d_in[1];  // [E,3E]
  const float* c_attn_b = (const float*)d_in[2];  // [3E]
  const float* c_proj_w = (const float*)d_in[3];  // [E,E]
  const float* c_proj_b = (const float*)d_in[4];  // [E]
  float* out = (float*)d_out;                     // [B,S,E] fp32

  char* ws = (char*)d_ws;
  unsigned short* hsb = (unsigned short*)(ws + 0);         // 8.39 MB [B,S,E] bf16
  unsigned short* qk  = (unsigned short*)(ws + 8388608);   // 16.8 MB [B,S,2048]
  unsigned short* vt  = (unsigned short*)(ws + 25165824);  // 8.39 MB [B,H,D,S] (key-permuted per 64-tile)
  unsigned short* aob = (unsigned short*)(ws + 33554432);  // 8.39 MB [B,S,E] bf16
  unsigned short* w1t = (unsigned short*)(ws + 41943040);  // 6.29 MB [3072,1024]
  unsigned short* w2t = (unsigned short*)(ws + 48234496);  // 2.10 MB [1024,1024]

  // 1) fused prepass: hs->bf16, transpose+convert both weight matrices
  prep<<<5120, 256, 0, stream>>>(hs, c_attn_w, c_proj_w, hsb, w1t, w2t);
  // 2) QKV GEMM (128x192 tiles, 512 blocks = exactly 2/CU, balanced) -> qk + vt
  gemm_pl<0, 192><<<512, 256, 0, stream>>>(hsb, w1t, c_attn_b, nullptr, qk, vt);
  // 3) attention: 1024-thr megablock (4 waves/SIMD + full staging dedup)
  attn13<<<256, 1024, 0, stream>>>(qk, vt, aob);
  // 4) output projection (BK=64, 16 rounds) -> fp32 out
  gemm_pl<2, 64><<<512, 256, 0, stream>>>(aob, w2t, c_proj_b, out, nullptr, nullptr);
}